// Round 10
// baseline (30.967 us; speedup 1.0000x reference)
//
#include <hip/hip_runtime.h>

// QuantumTTEmbedding: TT-factorized embedding lookup.
// id -> (i,j,k) = (id/1600, (id/40)%40, id%40).
// Per half h (real/imag):
//   out[d][f][e] = sum_{r,s} c1[0][i][d][r] * c2[r][j][f][s] * c3[s][k][e][0]
// Output [N][256] f32, flat (h*128 + d*32 + f*8 + e).
//
// R10 structure: WAVE-SPECIALIZED HALVES. Even waves compute real halves,
// odd waves imag halves; a wave-pair covers 32 tokens. Each iteration a
// wave processes 2 tokens (lane p = lane>>5 selects token A/B), so every
// ds_read serves 2 tokens via per-lane address select:
//   7 DS instrs / 2 tokens = 3.5/token (vs 7 in R7)  -> LDS ~9us << write
//   floor ~21us. Phase-1 rank-split + DPP quad_perm exchange kept from R7
//   (partner lane^1 = same token, other e-half). Store: one float4/lane =
//   two 512B segments per instr (full 64B lines).

#define V1 20
#define V2 40
#define V3 40
#define D1 4
#define D2 4
#define D3 8
#define RNK 4

#define C1_SZ (V1*D1*RNK)          // 320 floats
#define C2_SZ (RNK*V2*D2*RNK)      // 2560 floats
#define C3_SZ (RNK*V3*D3)          // 1280 floats
#define HALF_SZ (C1_SZ + C2_SZ + C3_SZ)   // 4160
#define IMAG_OFF (HALF_SZ + 16)    // 4176: imag base == 16 mod 32 banks
#define LDS_FLOATS (IMAG_OFF + HALF_SZ)   // 8336 floats = 33.4 KB

#define TPP 32                     // tokens per wave-PAIR (each wave: one half of 32 tokens)
#define BLOCK 512                  // 8 waves/block = 4 pairs -> 128 tokens/block

// quad_perm [1,0,3,2]: swap lanes differing in bit0 (the e0-pair, same token). Pure VALU.
__device__ __forceinline__ float dpp_swap1(float x) {
    int xi = __builtin_bit_cast(int, x);
    int yi = __builtin_amdgcn_mov_dpp(xi, 0xB1, 0xF, 0xF, true);
    return __builtin_bit_cast(float, yi);
}

__global__ __launch_bounds__(BLOCK, 8) void tt_embed_kernel(
    const int* __restrict__ ids,
    const float* __restrict__ cr1, const float* __restrict__ cr2, const float* __restrict__ cr3,
    const float* __restrict__ ci1, const float* __restrict__ ci2, const float* __restrict__ ci3,
    float* __restrict__ out, int N)
{
    __shared__ __align__(16) float lds[LDS_FLOATS];

    // ---- wave roles ----
    const int lane = threadIdx.x & 63;
    const int wid  = blockIdx.x * (BLOCK / 64) + (threadIdx.x >> 6);
    const int h    = wid & 1;            // 0 = real wave, 1 = imag wave
    const int t0   = (wid >> 1) * TPP;   // first token of this wave-pair
    const int nv   = (N - t0 < TPP) ? (N - t0) : TPP;   // tokens valid in pair

    // ---- issue this wave's 32 token ids FIRST (hide under staging) ----
    int id = 0;
    if (lane < 32 && lane < nv) id = ids[t0 + lane];

    // ---- stage cores into LDS, float4-vectorized ----
    {
        float4*       l4r = (float4*)lds;
        float4*       l4i = (float4*)(lds + IMAG_OFF);
        const float4* s1r = (const float4*)cr1; const float4* s1i = (const float4*)ci1;
        const float4* s2r = (const float4*)cr2; const float4* s2i = (const float4*)ci2;
        const float4* s3r = (const float4*)cr3; const float4* s3i = (const float4*)ci3;
        for (int idx = threadIdx.x; idx < C1_SZ/4; idx += BLOCK) {
            l4r[idx] = s1r[idx]; l4i[idx] = s1i[idx];
        }
        for (int idx = threadIdx.x; idx < C2_SZ/4; idx += BLOCK) {
            l4r[C1_SZ/4 + idx] = s2r[idx]; l4i[C1_SZ/4 + idx] = s2i[idx];
        }
        for (int idx = threadIdx.x; idx < C3_SZ/4; idx += BLOCK) {
            l4r[(C1_SZ+C2_SZ)/4 + idx] = s3r[idx]; l4i[(C1_SZ+C2_SZ)/4 + idx] = s3i[idx];
        }
    }

    // ---- decode id -> packed LDS float-offsets (overlaps staging) ----
    int packed = 0;
    if (lane < 32 && lane < nv) {
        const int k  = id % V3;
        const int ij = id / V3;
        const int j  = ij % V2;
        const int i  = ij / V2;
        // i*16 (9b) | j*16 << 9 (10b) | k*8 << 19 (9b)
        packed = (i * (D1*RNK)) | ((j * (D2*RNK)) << 9) | ((k * D3) << 19);
    }

    __syncthreads();

    // ---- lane decomposition: p = token select, q = (d,f,e0) within the half ----
    const int p    = lane >> 5;          // token A (0) or B (1) of this iteration
    const int q    = lane & 31;
    const int d    = q >> 3;             // 0..3
    const int f    = (q >> 1) & 3;       // 0..3
    const int e0   = (q & 1) * 4;        // 0 or 4
    const int roff = (q & 1) * 2;        // r-pair: {0,1} or {2,3}

    const float* base = lds + h * IMAG_OFF;
    const float* B1 = base + d * RNK + roff;             // + io -> g1[d][roff..roff+1]
    const float* B2 = base + C1_SZ + f * RNK;            // + jo + roff*640 -> g2[r][f][0..3]
    const float* B3 = base + C1_SZ + C2_SZ + e0;         // + ko + s*320 -> g3[s][e0..e0+3]

    // lane's output: token (t0 + 2*it + p), floats [h*128 + q*4 .. +3]
    float* outp = out + (size_t)(t0 + p) * 256 + h * 128 + q * 4;

    const int iters = (nv + 1) >> 1;
    #pragma unroll 1
    for (int it = 0; it < iters; ++it) {
        const int pA = __builtin_amdgcn_readlane(packed, 2*it);
        const int pB = __builtin_amdgcn_readlane(packed, 2*it + 1);
        const int sel = p ? pB : pA;                       // per-lane token select
        const int io = sel & 0x1ff;
        const int jo = (sel >> 9) & 0x3ff;
        const int ko = (sel >> 19);

        // phase 1 (rank-split): partial[s] = sum_{r in pair} g1[d][r]*g2[r][f][s]
        const float2 g1p = *reinterpret_cast<const float2*>(B1 + io);
        const float* p2  = B2 + jo + roff * (V2*D2*RNK);
        const float4 aA  = *reinterpret_cast<const float4*>(p2);
        const float4 aB  = *reinterpret_cast<const float4*>(p2 + (V2*D2*RNK));
        float t0p = g1p.x*aA.x + g1p.y*aB.x;
        float t1p = g1p.x*aA.y + g1p.y*aB.y;
        float t2p = g1p.x*aA.z + g1p.y*aB.z;
        float t3p = g1p.x*aA.w + g1p.y*aB.w;
        // exchange with e0-partner (lane^1, same token) and sum -> full tmp[s]
        const float tmp0 = t0p + dpp_swap1(t0p);
        const float tmp1 = t1p + dpp_swap1(t1p);
        const float tmp2 = t2p + dpp_swap1(t2p);
        const float tmp3 = t3p + dpp_swap1(t3p);

        // phase 2: out[e] = sum_s tmp[s] * g3[s][e0+e]
        const float* p3 = B3 + ko;
        const float4 b0 = *reinterpret_cast<const float4*>(p3);
        const float4 b1 = *reinterpret_cast<const float4*>(p3 +     V3*D3);
        const float4 b2 = *reinterpret_cast<const float4*>(p3 + 2 * V3*D3);
        const float4 b3 = *reinterpret_cast<const float4*>(p3 + 3 * V3*D3);
        float4 o;
        o.x = tmp0*b0.x + tmp1*b1.x + tmp2*b2.x + tmp3*b3.x;
        o.y = tmp0*b0.y + tmp1*b1.y + tmp2*b2.y + tmp3*b3.y;
        o.z = tmp0*b0.z + tmp1*b1.z + tmp2*b2.z + tmp3*b3.z;
        o.w = tmp0*b0.w + tmp1*b1.w + tmp2*b2.w + tmp3*b3.w;

        if (2*it + p < nv) {
            *reinterpret_cast<float4*>(outp) = o;
        }
        outp += 512;   // 2 tokens
    }
}

extern "C" void kernel_launch(void* const* d_in, const int* in_sizes, int n_in,
                              void* d_out, int out_size, void* d_ws, size_t ws_size,
                              hipStream_t stream) {
    const int*   ids = (const int*)d_in[0];
    const float* cr1 = (const float*)d_in[1];
    const float* cr2 = (const float*)d_in[2];
    const float* cr3 = (const float*)d_in[3];
    const float* ci1 = (const float*)d_in[4];
    const float* ci2 = (const float*)d_in[5];
    const float* ci3 = (const float*)d_in[6];
    float* out = (float*)d_out;

    const int N = in_sizes[0];
    const int tokens_per_block = (BLOCK / 128) * TPP;                  // 128
    const int blocks = (N + tokens_per_block - 1) / tokens_per_block;  // 1024 @ N=131072

    tt_embed_kernel<<<blocks, BLOCK, 0, stream>>>(ids, cr1, cr2, cr3, ci1, ci2, ci3, out, N);
}

// Round 11
// 27.910 us; speedup vs baseline: 1.1095x; 1.1095x over previous
//
#include <hip/hip_runtime.h>

// QuantumTTEmbedding: TT-factorized embedding lookup.
// id -> (i,j,k) = (id/1600, (id/40)%40, id%40).
// Per half h (real/imag):
//   out[d][f][e] = sum_{r,s} c1[0][i][d][r] * c2[r][j][f][s] * c3[s][k][e][0]
// Output [N][256] f32, flat (h*128 + d*32 + f*8 + e).
//
// R7 mapping (best, 29.0us): one wave per token; lane = (h,d,f,e-half),
// 4 outputs/lane -> one float4 store = 1KB contiguous per wave; rank-split
// phase 1 across the e0-pair (7 DS instrs/token: 1 b64 + 6 b128) with DPP
// quad_perm exchange. Proven constraints: stores must stay 1KB contiguous
// (R4/R10 fragmetation regressed); VALU & unroll null (R8/R9).
// R11 change (single variable): grid shape 1024 blocks/TPW16 -> 512
// blocks/TPW32. 2 blocks/CU instead of 4 -> half the concurrent HBM write
// streams, 2x longer per-wave contiguous runs (32 KB). Tests DRAM
// stream-locality as the residual vs the fill kernel's 6.5 TB/s.

#define V1 20
#define V2 40
#define V3 40
#define D1 4
#define D2 4
#define D3 8
#define RNK 4

#define C1_SZ (V1*D1*RNK)          // 320 floats
#define C2_SZ (RNK*V2*D2*RNK)      // 2560 floats
#define C3_SZ (RNK*V3*D3)          // 1280 floats
#define HALF_SZ (C1_SZ + C2_SZ + C3_SZ)   // 4160
#define IMAG_OFF (HALF_SZ + 16)    // 4176: imag base == 16 mod 32 banks
#define LDS_FLOATS (IMAG_OFF + HALF_SZ)   // 8336 floats = 33.4 KB

#define TPW 32                     // tokens per wave
#define BLOCK 512                  // 8 waves/block; 2 blocks/CU -> 16 waves/CU

// quad_perm [1,0,3,2]: swap lanes differing in bit0 (the e0-pair). Pure VALU.
__device__ __forceinline__ float dpp_swap1(float x) {
    int xi = __builtin_bit_cast(int, x);
    int yi = __builtin_amdgcn_mov_dpp(xi, 0xB1, 0xF, 0xF, true);
    return __builtin_bit_cast(float, yi);
}

__global__ __launch_bounds__(BLOCK, 8) void tt_embed_kernel(
    const int* __restrict__ ids,
    const float* __restrict__ cr1, const float* __restrict__ cr2, const float* __restrict__ cr3,
    const float* __restrict__ ci1, const float* __restrict__ ci2, const float* __restrict__ ci3,
    float* __restrict__ out, int N)
{
    __shared__ __align__(16) float lds[LDS_FLOATS];

    // ---- issue this wave's id loads FIRST (hide under staging) ----
    const int lane = threadIdx.x & 63;
    const int wid  = blockIdx.x * (BLOCK / 64) + (threadIdx.x >> 6);
    const int t0   = wid * TPW;
    const int nv   = (N - t0 < TPW) ? (N - t0) : TPW;
    int id = 0;
    if (lane < TPW && lane < nv) id = ids[t0 + lane];

    // ---- stage cores into LDS, float4-vectorized ----
    {
        float4*       l4r = (float4*)lds;
        float4*       l4i = (float4*)(lds + IMAG_OFF);
        const float4* s1r = (const float4*)cr1; const float4* s1i = (const float4*)ci1;
        const float4* s2r = (const float4*)cr2; const float4* s2i = (const float4*)ci2;
        const float4* s3r = (const float4*)cr3; const float4* s3i = (const float4*)ci3;
        for (int idx = threadIdx.x; idx < C1_SZ/4; idx += BLOCK) {
            l4r[idx] = s1r[idx]; l4i[idx] = s1i[idx];
        }
        for (int idx = threadIdx.x; idx < C2_SZ/4; idx += BLOCK) {
            l4r[C1_SZ/4 + idx] = s2r[idx]; l4i[C1_SZ/4 + idx] = s2i[idx];
        }
        for (int idx = threadIdx.x; idx < C3_SZ/4; idx += BLOCK) {
            l4r[(C1_SZ+C2_SZ)/4 + idx] = s3r[idx]; l4i[(C1_SZ+C2_SZ)/4 + idx] = s3i[idx];
        }
    }

    // ---- decode id -> packed LDS float-offsets (overlaps staging) ----
    int packed = 0;
    if (lane < TPW && lane < nv) {
        const int k  = id % V3;
        const int ij = id / V3;
        const int j  = ij % V2;
        const int i  = ij / V2;
        // i*16 (9b) | j*16 << 9 (10b) | k*8 << 19 (9b)
        packed = (i * (D1*RNK)) | ((j * (D2*RNK)) << 9) | ((k * D3) << 19);
    }

    __syncthreads();

    // ---- lane decomposition: one wave per token, 4 outputs per lane ----
    const int half = lane >> 5;          // 0 = real, 1 = imag
    const int q    = lane & 31;
    const int d    = q >> 3;             // 0..3
    const int f    = (q >> 1) & 3;       // 0..3
    const int e0   = (q & 1) * 4;        // 0 or 4
    const int roff = (q & 1) * 2;        // this lane's r-pair: {0,1} or {2,3}

    const float* base = lds + half * IMAG_OFF;
    const float* B1 = base + d * RNK + roff;             // + io -> g1[d][roff..roff+1]
    const float* B2 = base + C1_SZ + f * RNK;            // + jo + r*640 -> g2[r][f][0..3]
    const float* B3 = base + C1_SZ + C2_SZ + e0;         // + ko + s*320 -> g3[s][e0..e0+3]

    float* outp = out + (size_t)t0 * 256 + lane * 4;

    #pragma unroll 1
    for (int it = 0; it < nv; ++it) {
        const int p  = __builtin_amdgcn_readlane(packed, it);  // SGPR broadcast
        const int io = p & 0x1ff;
        const int jo = (p >> 9) & 0x3ff;
        const int ko = (p >> 19);

        // phase 1 (rank-split): partial[s] = sum_{r in pair} g1[d][r]*g2[r][f][s]
        const float2 g1p = *reinterpret_cast<const float2*>(B1 + io);
        const float* p2  = B2 + jo;
        const float4 aA  = *reinterpret_cast<const float4*>(p2 +  roff      * (V2*D2*RNK));
        const float4 aB  = *reinterpret_cast<const float4*>(p2 + (roff + 1) * (V2*D2*RNK));
        float t0p = g1p.x*aA.x + g1p.y*aB.x;
        float t1p = g1p.x*aA.y + g1p.y*aB.y;
        float t2p = g1p.x*aA.z + g1p.y*aB.z;
        float t3p = g1p.x*aA.w + g1p.y*aB.w;
        // exchange with e0-partner (lane^1) and sum -> full tmp[s]
        const float tmp0 = t0p + dpp_swap1(t0p);
        const float tmp1 = t1p + dpp_swap1(t1p);
        const float tmp2 = t2p + dpp_swap1(t2p);
        const float tmp3 = t3p + dpp_swap1(t3p);

        // phase 2: out[e] = sum_s tmp[s] * g3[s][e0+e]
        const float* p3 = B3 + ko;
        const float4 b0 = *reinterpret_cast<const float4*>(p3);
        const float4 b1 = *reinterpret_cast<const float4*>(p3 +     V3*D3);
        const float4 b2 = *reinterpret_cast<const float4*>(p3 + 2 * V3*D3);
        const float4 b3 = *reinterpret_cast<const float4*>(p3 + 3 * V3*D3);
        float4 o;
        o.x = tmp0*b0.x + tmp1*b1.x + tmp2*b2.x + tmp3*b3.x;
        o.y = tmp0*b0.y + tmp1*b1.y + tmp2*b2.y + tmp3*b3.y;
        o.z = tmp0*b0.z + tmp1*b1.z + tmp2*b2.z + tmp3*b3.z;
        o.w = tmp0*b0.w + tmp1*b1.w + tmp2*b2.w + tmp3*b3.w;

        *reinterpret_cast<float4*>(outp) = o;
        outp += 256;
    }
}

extern "C" void kernel_launch(void* const* d_in, const int* in_sizes, int n_in,
                              void* d_out, int out_size, void* d_ws, size_t ws_size,
                              hipStream_t stream) {
    const int*   ids = (const int*)d_in[0];
    const float* cr1 = (const float*)d_in[1];
    const float* cr2 = (const float*)d_in[2];
    const float* cr3 = (const float*)d_in[3];
    const float* ci1 = (const float*)d_in[4];
    const float* ci2 = (const float*)d_in[5];
    const float* ci3 = (const float*)d_in[6];
    float* out = (float*)d_out;

    const int N = in_sizes[0];
    const int tokens_per_block = (BLOCK / 64) * TPW;                   // 256
    const int blocks = (N + tokens_per_block - 1) / tokens_per_block;  // 512 @ N=131072

    tt_embed_kernel<<<blocks, BLOCK, 0, stream>>>(ids, cr1, cr2, cr3, ci1, ci2, ci3, out, N);
}